// Round 1
// baseline (355.679 us; speedup 1.0000x reference)
//
#include <hip/hip_runtime.h>

typedef unsigned int uint;
typedef unsigned short ushort;
typedef __attribute__((ext_vector_type(8))) short bf16x8;
typedef __attribute__((ext_vector_type(4))) float floatx4;

#define B_   64
#define NR_  16384
#define IC_  16
#define NC_  10
#define OC_  16
#define NCO  160   // NC_*OC_
#define KC_  32    // K chunks (512 r each)
#define KT_  32    // K tile per step
#define NSTEP 16   // (NR_/KC_)/KT_

__device__ __forceinline__ float bf2f(ushort h) {
    return __uint_as_float(((uint)h) << 16);
}
__device__ __forceinline__ ushort f2bf(float f) {  // RNE
    uint u = __float_as_uint(f);
    u += 0x7fffu + ((u >> 16) & 1u);
    return (ushort)(u >> 16);
}
// split fp32 -> (hi, lo) bf16 pair; hi+lo captures f to ~2^-18 rel.
__device__ __forceinline__ void splitbf(float f, ushort& h, ushort& l) {
    h = f2bf(f);
    l = f2bf(f - bf2f(h));   // subtraction exact (operands within 2^-9)
}
// squash: s^2*s/((1+s^2)*sqrt(s^2)) == s*|s|/(1+s^2)
__device__ __forceinline__ float squashf(float s) {
    return s * fabsf(s) / (1.0f + s * s);
}

// ---------------------------------------------------------------------------
// Transpose+split: xTh/xTl[i][b][r] (bf16) from x[b][r][i] (fp32).
// grid (chunk=16, b=64), 256 thr. chunk==0 blocks also zero uh (drops memset).
// ---------------------------------------------------------------------------
__global__ __launch_bounds__(256) void k_xT(const float* __restrict__ xf,
                                            ushort* __restrict__ xTh,
                                            ushort* __restrict__ xTl,
                                            float* __restrict__ uh)
{
    const int chunk = blockIdx.x, b = blockIdx.y, t = threadIdx.x;
    if (chunk == 0) {   // zero this b's uh slice (2560 floats)
        float4 z = {0.f, 0.f, 0.f, 0.f};
        float4* dst = (float4*)(uh + (size_t)b * (IC_ * NCO));
        for (int n = t; n < 640; n += 256) dst[n] = z;
    }
    const int r0 = chunk * 1024;
#pragma unroll
    for (int j = 0; j < 4; ++j) {
        int r = r0 + t + 256 * j;
        const float* row = xf + ((size_t)b * NR_ + r) * IC_;
        float vals[16];
        *(float4*)&vals[0]  = *(const float4*)row;
        *(float4*)&vals[4]  = *(const float4*)(row + 4);
        *(float4*)&vals[8]  = *(const float4*)(row + 8);
        *(float4*)&vals[12] = *(const float4*)(row + 12);
#pragma unroll
        for (int i = 0; i < 16; ++i) {
            ushort h, l;
            splitbf(vals[i], h, l);
            size_t idx = ((size_t)(i * B_ + b)) * NR_ + r;
            xTh[idx] = h;
            xTl[idx] = l;
        }
    }
}

// ---------------------------------------------------------------------------
// k_uhat helpers
// ---------------------------------------------------------------------------
__device__ __forceinline__ void loadW5(const float* __restrict__ wbase_st,
                                       int tid, float2* r)
{
#pragma unroll
    for (int s = 0; s < 5; ++s) {
        int idx2 = tid + 512 * s;           // [0,2560) float2 units
        int row  = idx2 >> 4;               // 16 float2 per 32-k row
        int e    = idx2 & 15;
        r[s] = *(const float2*)(wbase_st + (size_t)row * NR_ + 2 * e);
    }
}

__device__ __forceinline__ void storeW5(const float2* r, int tid,
                                        ushort* __restrict__ WhB,
                                        ushort* __restrict__ WlB)
{
#pragma unroll
    for (int s = 0; s < 5; ++s) {
        int idx2 = tid + 512 * s;
        int row  = idx2 >> 4;
        int e    = idx2 & 15;
        ushort h0, l0, h1, l1;
        splitbf(r[s].x, h0, l0);
        splitbf(r[s].y, h1, l1);
        *(uint*)&WhB[row * 40 + 2 * e] = (uint)h0 | ((uint)h1 << 16);
        *(uint*)&WlB[row * 40 + 2 * e] = (uint)l0 | ((uint)l1 << 16);
    }
}

__device__ __forceinline__ void loadX(const ushort* __restrict__ xTh,
                                      const ushort* __restrict__ xTl,
                                      size_t xrow, int st, int has_xt,
                                      const float* __restrict__ xf,
                                      int b, int i, int r0, int quad,
                                      bf16x8& h, bf16x8& l)
{
    if (has_xt) {
        size_t o = xrow + (size_t)st * KT_;
        h = *(const bf16x8*)&xTh[o];
        l = *(const bf16x8*)&xTl[o];
    } else {
#pragma unroll
        for (int q = 0; q < 8; ++q) {
            float v = xf[((size_t)b * NR_ + r0 + st * KT_ + quad * 8 + q) * IC_ + i];
            ushort hh, ll;
            splitbf(v, hh, ll);
            h[q] = (short)hh;
            l[q] = (short)ll;
        }
    }
}

__device__ __forceinline__ void mfma5(const ushort* __restrict__ WhB,
                                      const ushort* __restrict__ WlB,
                                      bf16x8 ah, bf16x8 al,
                                      floatx4* acc, int cg, int m16, int quad)
{
#pragma unroll
    for (int t5 = 0; t5 < 5; ++t5) {
        int corow = (cg * 5 + t5) * 16 + m16;
        bf16x8 bh = *(const bf16x8*)&WhB[corow * 40 + quad * 8];
        bf16x8 bl = *(const bf16x8*)&WlB[corow * 40 + quad * 8];
        acc[t5] = __builtin_amdgcn_mfma_f32_16x16x32_bf16(ah, bh, acc[t5], 0, 0, 0);
        acc[t5] = __builtin_amdgcn_mfma_f32_16x16x32_bf16(al, bh, acc[t5], 0, 0, 0);
        acc[t5] = __builtin_amdgcn_mfma_f32_16x16x32_bf16(ah, bl, acc[t5], 0, 0, 0);
    }
}

// ---------------------------------------------------------------------------
// u_hat[b][i][co] = sum_r W[i][co][r] * x[b][r][i]
// Depth-2 pipelined: W global->reg one step ahead, reg->LDS (double buffered,
// split hi/lo) one step late; x frags direct from pre-split planes one step
// ahead. One barrier per step. grid (i=16, kc=KC_), 512 thr (8 waves).
// ---------------------------------------------------------------------------
__global__ __launch_bounds__(512, 4) void k_uhat(const float* __restrict__ xf,
                                                 const float* __restrict__ wf,
                                                 const ushort* __restrict__ xTh,
                                                 const ushort* __restrict__ xTl,
                                                 int has_xt,
                                                 float* __restrict__ uh)
{
    const int i    = blockIdx.x;
    const int kc   = blockIdx.y;
    const int tid  = threadIdx.x;
    const int lane = tid & 63;
    const int w    = tid >> 6;
    const int quad = lane >> 4;
    const int m16  = lane & 15;
    const int bt   = w & 3;    // b-tile (16 b's)
    const int cg   = w >> 2;   // co-group (5 co-tiles each)

    // W double buffer, row stride 40 elems (80B, 16B-aligned rows)
    __shared__ ushort Wh[2][160 * 40];
    __shared__ ushort Wl[2][160 * 40];

    floatx4 acc[5];
#pragma unroll
    for (int t = 0; t < 5; ++t) acc[t] = (floatx4){0.f, 0.f, 0.f, 0.f};

    const int r0 = kc * (NR_ / KC_);
    const float* wbase = wf + (size_t)i * NCO * NR_ + r0;
    const int xb = bt * 16 + m16;
    const size_t xrow = (size_t)(i * B_ + xb) * NR_ + r0 + quad * 8;

    float2 wA[5], wB[5];
    bf16x8 xhA, xlA, xhB, xlB;

    // prologue: W0 -> LDS buf0 ; W1 in flight ; X0 in regs
    loadW5(wbase, tid, wA);
    loadX(xTh, xTl, xrow, 0, has_xt, xf, xb, i, r0, quad, xhA, xlA);
    storeW5(wA, tid, Wh[0], Wl[0]);
    loadW5(wbase + 1 * KT_, tid, wB);
    __syncthreads();

    for (int st = 0; st < NSTEP; st += 2) {
        // even step st: compute buf0/X(st); stage W(st+1)->buf1; prefetch W(st+2),X(st+1)
        loadX(xTh, xTl, xrow, st + 1, has_xt, xf, xb, i, r0, quad, xhB, xlB);
        storeW5(wB, tid, Wh[1], Wl[1]);
        if (st + 2 < NSTEP) loadW5(wbase + (size_t)(st + 2) * KT_, tid, wA);
        mfma5(Wh[0], Wl[0], xhA, xlA, acc, cg, m16, quad);
        __syncthreads();

        // odd step st+1: compute buf1/X(st+1); stage W(st+2)->buf0; prefetch W(st+3),X(st+2)
        if (st + 2 < NSTEP) {
            loadX(xTh, xTl, xrow, st + 2, has_xt, xf, xb, i, r0, quad, xhA, xlA);
            storeW5(wA, tid, Wh[0], Wl[0]);
        }
        if (st + 3 < NSTEP) loadW5(wbase + (size_t)(st + 3) * KT_, tid, wB);
        mfma5(Wh[1], Wl[1], xhB, xlB, acc, cg, m16, quad);
        __syncthreads();
    }

    // epilogue: C/D col=lane&15 (co), row=quad*4+reg (b in tile)
#pragma unroll
    for (int t5 = 0; t5 < 5; ++t5) {
        int co = (cg * 5 + t5) * 16 + m16;
#pragma unroll
        for (int r = 0; r < 4; ++r) {
            int b = bt * 16 + quad * 4 + r;
            atomicAdd(&uh[(b * IC_ + i) * NCO + co], acc[t5][r]);
        }
    }
}

// ---------------------------------------------------------------------------
// All 3 routing iterations + FC head in ONE kernel. 64 blocks; each block
// redundantly recomputes the (tiny) global b_ij/c_ij chain from L2-resident
// uh, then writes only its own b's v3 + pred. No grid sync, no atomics.
// out (fp32): [0:64) pred, [64:10304) v3[b][c][o].
// ---------------------------------------------------------------------------
__global__ __launch_bounds__(256) void k_route(const float* __restrict__ uh,
                                               const float* __restrict__ fcw,
                                               const float* __restrict__ fcb,
                                               float* __restrict__ out)
{
    const int bo = blockIdx.x, t = threadIdx.x;
    __shared__ float vL[B_ * NCO];   // 40 KB: v_j for all b
    __shared__ float a1L[160];       // a1[c*16+i]
    __shared__ float bL[160];        // b2[c*16+i]; reused as pL at the end
    __shared__ float cL[160];        // c_ij[c*16+i]

    // ---- iter 1: v1 = squash(mean_i u)  (c uniform = 1/16) ----
    for (int q4 = t; q4 < 2560; q4 += 256) {      // 2560 float4 = 64b x 40
        int b = q4 / 40, r = q4 - b * 40;
        const float4* up = (const float4*)(uh + (size_t)b * 2560 + r * 4);
        float4 s = {0.f, 0.f, 0.f, 0.f};
#pragma unroll
        for (int i2 = 0; i2 < 16; ++i2) {
            float4 u4 = up[i2 * 40];
            s.x += u4.x; s.y += u4.y; s.z += u4.z; s.w += u4.w;
        }
        float4 v;
        v.x = squashf(s.x * 0.0625f);
        v.y = squashf(s.y * 0.0625f);
        v.z = squashf(s.z * 0.0625f);
        v.w = squashf(s.w * 0.0625f);
        *((float4*)vL + q4) = v;
    }
    __syncthreads();
    // ---- a1[i,c] = (1/64) sum_{b,o} u * v1 ----
    if (t < 160) {
        int c = t >> 4, i2 = t & 15;
        const float* up0 = uh + i2 * NCO + c * 16;
        const float* vp0 = vL + c * 16;
        float4 s4 = {0.f, 0.f, 0.f, 0.f};
        for (int b = 0; b < 64; ++b) {
            const float4* up = (const float4*)(up0 + (size_t)b * 2560);
            const float4* vp = (const float4*)(vp0 + b * 160);
#pragma unroll
            for (int q = 0; q < 4; ++q) {
                float4 u4 = up[q], v4 = vp[q];
                s4.x += u4.x * v4.x; s4.y += u4.y * v4.y;
                s4.z += u4.z * v4.z; s4.w += u4.w * v4.w;
            }
        }
        a1L[t] = ((s4.x + s4.y) + (s4.z + s4.w)) * (1.0f / 64.0f);
    }
    __syncthreads();
    // ---- c2 = softmax_i(a1) ----
    if (t < 160) {
        int c = t >> 4;
        float m = -1e30f;
#pragma unroll
        for (int i2 = 0; i2 < 16; ++i2) m = fmaxf(m, a1L[c * 16 + i2]);
        float Z = 0.f;
#pragma unroll
        for (int i2 = 0; i2 < 16; ++i2) Z += expf(a1L[c * 16 + i2] - m);
        cL[t] = expf(a1L[t] - m) / Z;
    }
    __syncthreads();
    // ---- iter 2: v2 = squash(sum_i c2*u) ----
    for (int q4 = t; q4 < 2560; q4 += 256) {
        int b = q4 / 40, r = q4 - b * 40;
        int c = r >> 2;                            // 4 float4 per capsule c
        const float4* up = (const float4*)(uh + (size_t)b * 2560 + r * 4);
        float4 s = {0.f, 0.f, 0.f, 0.f};
#pragma unroll
        for (int i2 = 0; i2 < 16; ++i2) {
            float w2 = cL[c * 16 + i2];
            float4 u4 = up[i2 * 40];
            s.x += w2 * u4.x; s.y += w2 * u4.y;
            s.z += w2 * u4.z; s.w += w2 * u4.w;
        }
        float4 v;
        v.x = squashf(s.x); v.y = squashf(s.y);
        v.z = squashf(s.z); v.w = squashf(s.w);
        *((float4*)vL + q4) = v;
    }
    __syncthreads();
    // ---- a2; b2 = a1 + a2 ----
    if (t < 160) {
        int c = t >> 4, i2 = t & 15;
        const float* up0 = uh + i2 * NCO + c * 16;
        const float* vp0 = vL + c * 16;
        float4 s4 = {0.f, 0.f, 0.f, 0.f};
        for (int b = 0; b < 64; ++b) {
            const float4* up = (const float4*)(up0 + (size_t)b * 2560);
            const float4* vp = (const float4*)(vp0 + b * 160);
#pragma unroll
            for (int q = 0; q < 4; ++q) {
                float4 u4 = up[q], v4 = vp[q];
                s4.x += u4.x * v4.x; s4.y += u4.y * v4.y;
                s4.z += u4.z * v4.z; s4.w += u4.w * v4.w;
            }
        }
        bL[t] = a1L[t] + ((s4.x + s4.y) + (s4.z + s4.w)) * (1.0f / 64.0f);
    }
    __syncthreads();
    // ---- c3 = softmax_i(b2) ----
    if (t < 160) {
        int c = t >> 4;
        float m = -1e30f;
#pragma unroll
        for (int i2 = 0; i2 < 16; ++i2) m = fmaxf(m, bL[c * 16 + i2]);
        float Z = 0.f;
#pragma unroll
        for (int i2 = 0; i2 < 16; ++i2) Z += expf(bL[c * 16 + i2] - m);
        cL[t] = expf(bL[t] - m) / Z;
    }
    __syncthreads();
    // ---- iter 3 (own b only): v3, FC partials ----
    if (t < 160) {
        int c = t >> 4;
        const float* ub = uh + (size_t)bo * 2560 + t;
        float s = 0.f;
#pragma unroll
        for (int i2 = 0; i2 < 16; ++i2) s += cL[c * 16 + i2] * ub[i2 * NCO];
        float v = squashf(s);
        out[64 + bo * NCO + t] = v;
        bL[t] = v * fcw[t];                        // reuse bL as pL
    }
    __syncthreads();
    if (t == 0) {
        float a = fcb[0];
        for (int j = 0; j < 160; ++j) a += bL[j];
        out[bo] = 1.0f / (1.0f + expf(-a));
    }
}

extern "C" void kernel_launch(void* const* d_in, const int* in_sizes, int n_in,
                              void* d_out, int out_size, void* d_ws, size_t ws_size,
                              hipStream_t stream)
{
    const float* x   = (const float*)d_in[0];
    const float* W   = (const float*)d_in[1];
    const float* fcw = (const float*)d_in[2];
    const float* fcb = (const float*)d_in[3];
    float* out = (float*)d_out;

    float* uh = (float*)d_ws;                      // 163840 fp32
    const size_t xt_off   = 1u << 20;              // 1 MB
    const size_t xt_bytes = (size_t)IC_ * B_ * NR_ * 2;  // 33.5 MB per plane
    ushort* xTh = (ushort*)((char*)d_ws + xt_off);
    ushort* xTl = (ushort*)((char*)d_ws + xt_off + xt_bytes);
    const int has_xt = (ws_size >= xt_off + 2 * xt_bytes) ? 1 : 0;  // host-const

    if (has_xt) {
        k_xT<<<dim3(16, 64), 256, 0, stream>>>(x, xTh, xTl, uh);   // also zeroes uh
    } else {
        hipMemsetAsync(uh, 0, (size_t)(B_ * IC_ * NCO) * sizeof(float), stream);
    }
    k_uhat<<<dim3(IC_, KC_), 512, 0, stream>>>(x, W, xTh, xTl, has_xt, uh);
    k_route<<<B_, 256, 0, stream>>>(uh, fcw, fcb, out);
}

// Round 3
// 353.638 us; speedup vs baseline: 1.0058x; 1.0058x over previous
//
#include <hip/hip_runtime.h>

typedef unsigned int uint;
typedef unsigned short ushort;
typedef __attribute__((ext_vector_type(8))) short bf16x8;
typedef __attribute__((ext_vector_type(4))) float floatx4;
typedef __attribute__((ext_vector_type(4))) uint uint4v;

#define B_   64
#define NR_  16384
#define IC_  16
#define NC_  10
#define OC_  16
#define NCO  160   // NC_*OC_
#define KC_  32    // K chunks (512 r each)
#define KT_  32    // K tile per step
#define NSTEP 16   // (NR_/KC_)/KT_

__device__ __forceinline__ float bf2f(ushort h) {
    return __uint_as_float(((uint)h) << 16);
}
__device__ __forceinline__ ushort f2bf(float f) {  // RNE
    uint u = __float_as_uint(f);
    u += 0x7fffu + ((u >> 16) & 1u);
    return (ushort)(u >> 16);
}
// split fp32 -> (hi, lo) bf16 pair; hi+lo captures f to ~2^-18 rel.
__device__ __forceinline__ void splitbf(float f, ushort& h, ushort& l) {
    h = f2bf(f);
    l = f2bf(f - bf2f(h));   // subtraction exact (operands within 2^-9)
}
// squash: s^2*s/((1+s^2)*sqrt(s^2)) == s*|s|/(1+s^2)
__device__ __forceinline__ float squashf(float s) {
    return s * fabsf(s) / (1.0f + s * s);
}

// ---------------------------------------------------------------------------
// Transpose+split: xTh/xTl[i][b][r] (bf16) from x[b][r][i] (fp32).
// grid (chunk=16, b=64), 256 thr. chunk==0 blocks also zero uh (drops memset).
// ---------------------------------------------------------------------------
__global__ __launch_bounds__(256) void k_xT(const float* __restrict__ xf,
                                            ushort* __restrict__ xTh,
                                            ushort* __restrict__ xTl,
                                            float* __restrict__ uh)
{
    const int chunk = blockIdx.x, b = blockIdx.y, t = threadIdx.x;
    if (chunk == 0) {   // zero this b's uh slice (2560 floats)
        float4 z = {0.f, 0.f, 0.f, 0.f};
        float4* dst = (float4*)(uh + (size_t)b * (IC_ * NCO));
        for (int n = t; n < 640; n += 256) dst[n] = z;
    }
    const int r0 = chunk * 1024;
#pragma unroll
    for (int j = 0; j < 4; ++j) {
        int r = r0 + t + 256 * j;
        const float* row = xf + ((size_t)b * NR_ + r) * IC_;
        float vals[16];
        *(float4*)&vals[0]  = *(const float4*)row;
        *(float4*)&vals[4]  = *(const float4*)(row + 4);
        *(float4*)&vals[8]  = *(const float4*)(row + 8);
        *(float4*)&vals[12] = *(const float4*)(row + 12);
#pragma unroll
        for (int i = 0; i < 16; ++i) {
            ushort h, l;
            splitbf(vals[i], h, l);
            size_t idx = ((size_t)(i * B_ + b)) * NR_ + r;
            xTh[idx] = h;
            xTl[idx] = l;
        }
    }
}

// ---------------------------------------------------------------------------
// k_uhat helpers: uniform W mapping, 5 x float2 per thread per 32-k step.
// ---------------------------------------------------------------------------
__device__ __forceinline__ void loadW5(const float* __restrict__ wbase_st,
                                       int tid, float2* r)
{
#pragma unroll
    for (int s = 0; s < 5; ++s) {
        int idx2 = tid + 512 * s;           // [0,2560) float2 units
        int row  = idx2 >> 4;               // 16 float2 per 32-k row
        int e    = idx2 & 15;
        r[s] = *(const float2*)(wbase_st + (size_t)row * NR_ + 2 * e);
    }
}

__device__ __forceinline__ void storeW5(const float2* r, int tid,
                                        ushort* __restrict__ WhB,
                                        ushort* __restrict__ WlB)
{
#pragma unroll
    for (int s = 0; s < 5; ++s) {
        int idx2 = tid + 512 * s;
        int row  = idx2 >> 4;
        int e    = idx2 & 15;
        ushort h0, l0, h1, l1;
        splitbf(r[s].x, h0, l0);
        splitbf(r[s].y, h1, l1);
        *(uint*)&WhB[row * 40 + 2 * e] = (uint)h0 | ((uint)h1 << 16);
        *(uint*)&WlB[row * 40 + 2 * e] = (uint)l0 | ((uint)l1 << 16);
    }
}

// ---------------------------------------------------------------------------
// u_hat[b][i][co] = sum_r W[i][co][r] * x[b][r][i]
// Round-0 proven structure (single LDS buffer, coalesced staged X) + depth-1
// REGISTER prefetch: next-step W/X global loads are issued before the
// convert/store VALU block, so HBM latency hides under convert+MFMA+barrier.
// grid (i=16, kc=KC_), 512 thr (8 waves), 64(b) x 160(co) x 32(k) tiles.
// ---------------------------------------------------------------------------
__global__ __launch_bounds__(512) void k_uhat(const float* __restrict__ xf,
                                              const float* __restrict__ wf,
                                              const ushort* __restrict__ xTh,
                                              const ushort* __restrict__ xTl,
                                              int has_xt,
                                              float* __restrict__ uh)
{
    const int i    = blockIdx.x;
    const int kc   = blockIdx.y;
    const int tid  = threadIdx.x;
    const int lane = tid & 63;
    const int w    = tid >> 6;
    const int quad = lane >> 4;
    const int m16  = lane & 15;
    const int bt   = w & 3;    // b-tile (16 b's)
    const int cg   = w >> 2;   // co-group (5 co-tiles each)

    // row stride 40 elems (80B): b128 frag reads are 2-way bank aliased (free)
    __shared__ ushort Xh[64 * 40], Xl[64 * 40];
    __shared__ ushort Wh[160 * 40], Wl[160 * 40];

    floatx4 acc[5];
#pragma unroll
    for (int t = 0; t < 5; ++t) acc[t] = (floatx4){0.f, 0.f, 0.f, 0.f};

    const int r0 = kc * (NR_ / KC_);
    const float* wbase = wf + (size_t)i * NCO * NR_ + r0;

    // X staging role: tid<256 -> Xh plane, tid>=256 -> Xl plane (coalesced).
    const int t8 = tid & 255, bb = t8 >> 2, part = t8 & 3;
    const ushort* xplane = (tid < 256) ? xTh : xTl;
    ushort* xdst = (tid < 256) ? &Xh[bb * 40 + part * 8] : &Xl[bb * 40 + part * 8];
    const size_t xsrc0 = (size_t)(i * B_ + bb) * NR_ + r0 + part * 8;

    float2 wr[5];
    uint4v xr;

    // prologue: issue st=0 loads
    loadW5(wbase, tid, wr);
    if (has_xt) xr = *(const uint4v*)&xplane[xsrc0];

    for (int st = 0; st < NSTEP; ++st) {
        const int rb = r0 + st * KT_;
        // snapshot prefetched regs, then issue NEXT step's loads before the
        // convert chain (source order forces loads ahead of the VALU block)
        float2 wc[5];
#pragma unroll
        for (int s = 0; s < 5; ++s) wc[s] = wr[s];
        uint4v xc = xr;
        if (st + 1 < NSTEP) {
            loadW5(wbase + (size_t)(st + 1) * KT_, tid, wr);
            if (has_xt) xr = *(const uint4v*)&xplane[xsrc0 + (size_t)(st + 1) * KT_];
        }

        __syncthreads();   // previous compute done reading LDS
        // ---- stage X tile (64 b x 32 k, hi+lo) ----
        if (has_xt) {
            *(uint4v*)xdst = xc;
        } else {
#pragma unroll
            for (int s = 0; s < 4; ++s) {
                int n = tid + 512 * s;
                int bb2 = n >> 5, k = n & 31;
                float v = xf[(size_t)bb2 * (NR_ * IC_) + (size_t)(rb + k) * IC_ + i];
                ushort h, l;
                splitbf(v, h, l);
                Xh[bb2 * 40 + k] = h;
                Xl[bb2 * 40 + k] = l;
            }
        }
        // ---- stage W tile (160 co x 32 k, fp32 -> hi+lo) ----
        storeW5(wc, tid, Wh, Wl);
        __syncthreads();
        // ---- MFMA: A[m=lane&15][k=quad*8+j]; B row = co, same k layout ----
        bf16x8 afh = *(const bf16x8*)&Xh[(bt * 16 + m16) * 40 + quad * 8];
        bf16x8 afl = *(const bf16x8*)&Xl[(bt * 16 + m16) * 40 + quad * 8];
#pragma unroll
        for (int t5 = 0; t5 < 5; ++t5) {
            int corow = (cg * 5 + t5) * 16 + m16;
            bf16x8 bh = *(const bf16x8*)&Wh[corow * 40 + quad * 8];
            bf16x8 bl = *(const bf16x8*)&Wl[corow * 40 + quad * 8];
            acc[t5] = __builtin_amdgcn_mfma_f32_16x16x32_bf16(afh, bh, acc[t5], 0, 0, 0);
            acc[t5] = __builtin_amdgcn_mfma_f32_16x16x32_bf16(afl, bh, acc[t5], 0, 0, 0);
            acc[t5] = __builtin_amdgcn_mfma_f32_16x16x32_bf16(afh, bl, acc[t5], 0, 0, 0);
        }
    }
    // epilogue: C/D col=lane&15 (co), row=quad*4+reg (b in tile)
#pragma unroll
    for (int t5 = 0; t5 < 5; ++t5) {
        int co = (cg * 5 + t5) * 16 + m16;
#pragma unroll
        for (int r = 0; r < 4; ++r) {
            int b = bt * 16 + quad * 4 + r;
            atomicAdd(&uh[(b * IC_ + i) * NCO + co], acc[t5][r]);
        }
    }
}

// ---------------------------------------------------------------------------
// All 3 routing iterations + FC head in ONE kernel. 64 blocks; each block
// redundantly recomputes the (tiny) global b_ij/c_ij chain from L2-resident
// uh, then writes only its own b's v3 + pred. No grid sync, no atomics.
// out (fp32): [0:64) pred, [64:10304) v3[b][c][o].
// ---------------------------------------------------------------------------
__global__ __launch_bounds__(256) void k_route(const float* __restrict__ uh,
                                               const float* __restrict__ fcw,
                                               const float* __restrict__ fcb,
                                               float* __restrict__ out)
{
    const int bo = blockIdx.x, t = threadIdx.x;
    __shared__ float vL[B_ * NCO];   // 40 KB: v_j for all b
    __shared__ float a1L[160];       // a1[c*16+i]
    __shared__ float bL[160];        // b2[c*16+i]; reused as pL at the end
    __shared__ float cL[160];        // c_ij[c*16+i]

    // ---- iter 1: v1 = squash(mean_i u)  (c uniform = 1/16) ----
    for (int q4 = t; q4 < 2560; q4 += 256) {      // 2560 float4 = 64b x 40
        int b = q4 / 40, r = q4 - b * 40;
        const float4* up = (const float4*)(uh + (size_t)b * 2560 + r * 4);
        float4 s = {0.f, 0.f, 0.f, 0.f};
#pragma unroll
        for (int i2 = 0; i2 < 16; ++i2) {
            float4 u4 = up[i2 * 40];
            s.x += u4.x; s.y += u4.y; s.z += u4.z; s.w += u4.w;
        }
        float4 v;
        v.x = squashf(s.x * 0.0625f);
        v.y = squashf(s.y * 0.0625f);
        v.z = squashf(s.z * 0.0625f);
        v.w = squashf(s.w * 0.0625f);
        *((float4*)vL + q4) = v;
    }
    __syncthreads();
    // ---- a1[i,c] = (1/64) sum_{b,o} u * v1 ----
    if (t < 160) {
        int c = t >> 4, i2 = t & 15;
        const float* up0 = uh + i2 * NCO + c * 16;
        const float* vp0 = vL + c * 16;
        float4 s4 = {0.f, 0.f, 0.f, 0.f};
        for (int b = 0; b < 64; ++b) {
            const float4* up = (const float4*)(up0 + (size_t)b * 2560);
            const float4* vp = (const float4*)(vp0 + b * 160);
#pragma unroll
            for (int q = 0; q < 4; ++q) {
                float4 u4 = up[q], v4 = vp[q];
                s4.x += u4.x * v4.x; s4.y += u4.y * v4.y;
                s4.z += u4.z * v4.z; s4.w += u4.w * v4.w;
            }
        }
        a1L[t] = ((s4.x + s4.y) + (s4.z + s4.w)) * (1.0f / 64.0f);
    }
    __syncthreads();
    // ---- c2 = softmax_i(a1) ----
    if (t < 160) {
        int c = t >> 4;
        float m = -1e30f;
#pragma unroll
        for (int i2 = 0; i2 < 16; ++i2) m = fmaxf(m, a1L[c * 16 + i2]);
        float Z = 0.f;
#pragma unroll
        for (int i2 = 0; i2 < 16; ++i2) Z += expf(a1L[c * 16 + i2] - m);
        cL[t] = expf(a1L[t] - m) / Z;
    }
    __syncthreads();
    // ---- iter 2: v2 = squash(sum_i c2*u) ----
    for (int q4 = t; q4 < 2560; q4 += 256) {
        int b = q4 / 40, r = q4 - b * 40;
        int c = r >> 2;                            // 4 float4 per capsule c
        const float4* up = (const float4*)(uh + (size_t)b * 2560 + r * 4);
        float4 s = {0.f, 0.f, 0.f, 0.f};
#pragma unroll
        for (int i2 = 0; i2 < 16; ++i2) {
            float w2 = cL[c * 16 + i2];
            float4 u4 = up[i2 * 40];
            s.x += w2 * u4.x; s.y += w2 * u4.y;
            s.z += w2 * u4.z; s.w += w2 * u4.w;
        }
        float4 v;
        v.x = squashf(s.x); v.y = squashf(s.y);
        v.z = squashf(s.z); v.w = squashf(s.w);
        *((float4*)vL + q4) = v;
    }
    __syncthreads();
    // ---- a2; b2 = a1 + a2 ----
    if (t < 160) {
        int c = t >> 4, i2 = t & 15;
        const float* up0 = uh + i2 * NCO + c * 16;
        const float* vp0 = vL + c * 16;
        float4 s4 = {0.f, 0.f, 0.f, 0.f};
        for (int b = 0; b < 64; ++b) {
            const float4* up = (const float4*)(up0 + (size_t)b * 2560);
            const float4* vp = (const float4*)(vp0 + b * 160);
#pragma unroll
            for (int q = 0; q < 4; ++q) {
                float4 u4 = up[q], v4 = vp[q];
                s4.x += u4.x * v4.x; s4.y += u4.y * v4.y;
                s4.z += u4.z * v4.z; s4.w += u4.w * v4.w;
            }
        }
        bL[t] = a1L[t] + ((s4.x + s4.y) + (s4.z + s4.w)) * (1.0f / 64.0f);
    }
    __syncthreads();
    // ---- c3 = softmax_i(b2) ----
    if (t < 160) {
        int c = t >> 4;
        float m = -1e30f;
#pragma unroll
        for (int i2 = 0; i2 < 16; ++i2) m = fmaxf(m, bL[c * 16 + i2]);
        float Z = 0.f;
#pragma unroll
        for (int i2 = 0; i2 < 16; ++i2) Z += expf(bL[c * 16 + i2] - m);
        cL[t] = expf(bL[t] - m) / Z;
    }
    __syncthreads();
    // ---- iter 3 (own b only): v3, FC partials ----
    if (t < 160) {
        int c = t >> 4;
        const float* ub = uh + (size_t)bo * 2560 + t;
        float s = 0.f;
#pragma unroll
        for (int i2 = 0; i2 < 16; ++i2) s += cL[c * 16 + i2] * ub[i2 * NCO];
        float v = squashf(s);
        out[64 + bo * NCO + t] = v;
        bL[t] = v * fcw[t];                        // reuse bL as pL
    }
    __syncthreads();
    if (t == 0) {
        float a = fcb[0];
        for (int j = 0; j < 160; ++j) a += bL[j];
        out[bo] = 1.0f / (1.0f + expf(-a));
    }
}

extern "C" void kernel_launch(void* const* d_in, const int* in_sizes, int n_in,
                              void* d_out, int out_size, void* d_ws, size_t ws_size,
                              hipStream_t stream)
{
    const float* x   = (const float*)d_in[0];
    const float* W   = (const float*)d_in[1];
    const float* fcw = (const float*)d_in[2];
    const float* fcb = (const float*)d_in[3];
    float* out = (float*)d_out;

    float* uh = (float*)d_ws;                      // 163840 fp32
    const size_t xt_off   = 1u << 20;              // 1 MB
    const size_t xt_bytes = (size_t)IC_ * B_ * NR_ * 2;  // 33.5 MB per plane
    ushort* xTh = (ushort*)((char*)d_ws + xt_off);
    ushort* xTl = (ushort*)((char*)d_ws + xt_off + xt_bytes);
    const int has_xt = (ws_size >= xt_off + 2 * xt_bytes) ? 1 : 0;  // host-const

    if (has_xt) {
        k_xT<<<dim3(16, 64), 256, 0, stream>>>(x, xTh, xTl, uh);   // also zeroes uh
    } else {
        hipMemsetAsync(uh, 0, (size_t)(B_ * IC_ * NCO) * sizeof(float), stream);
    }
    k_uhat<<<dim3(IC_, KC_), 512, 0, stream>>>(x, W, xTh, xTl, has_xt, uh);
    k_route<<<B_, 256, 0, stream>>>(uh, fcw, fcb, out);
}